// Round 9
// baseline (2136.027 us; speedup 1.0000x reference)
//
#include <hip/hip_runtime.h>
#include <hip/hip_fp16.h>

#define BB 64
#define SS 1024
#define II 128
#define HH 256
#define OO 128

#if __has_builtin(__builtin_amdgcn_fdot2)
#define HAVE_DOT2 1
#endif

typedef __fp16 h2_t __attribute__((ext_vector_type(2)));

__device__ __forceinline__ unsigned packh(float a, float b) {
    union { h2_t h; unsigned u; } cv;
    cv.h = __builtin_amdgcn_cvt_pkrtz(a, b);   // v_cvt_pkrtz_f16_f32
    return cv.u;
}

__device__ __forceinline__ float dot2acc(unsigned w, unsigned h, float acc) {
#ifdef HAVE_DOT2
    union { unsigned u; h2_t h; } cw, ch;
    cw.u = w; ch.u = h;
    return __builtin_amdgcn_fdot2(cw.h, ch.h, acc, false);
#else
    union { unsigned u; __half2 h; } cw, ch;
    cw.u = w; ch.u = h;
    float2 a = __half22float2(cw.h), b = __half22float2(ch.h);
    return fmaf(a.x, b.x, fmaf(a.y, b.y, acc));
#endif
}

// fast transcendentals: error ~1e-6, below the f16-weight noise floor.
__device__ __forceinline__ float fsigmoid(float x) {
    float e = __builtin_amdgcn_exp2f(-1.4426950408889634f * x);
    return __builtin_amdgcn_rcpf(1.0f + e);
}
__device__ __forceinline__ float ftanh(float x) {
    float e = __builtin_amdgcn_exp2f(2.8853900817779268f * x);   // e^(2x)
    return 1.0f - 2.0f * __builtin_amdgcn_rcpf(1.0f + e);
}

// barrier without vmcnt drain: per-step global store / prefetch stay in flight.
__device__ __forceinline__ void bar_lds() {
    asm volatile("s_waitcnt lgkmcnt(0)\n\ts_barrier" ::: "memory");
}

// ---------------------------------------------------------------------------
// Kernel A: inp[b,t,h] = x[b,t,:] @ W_in[h,:] + (b_in[h] + b_rec[h])
// readfirstlane makes the W address provably wave-uniform -> s_load path
// (round-7 verified: A+C dropped 1073 -> 399us).
// ---------------------------------------------------------------------------
__global__ __launch_bounds__(256)
void ltc_inproj(const float* __restrict__ x, const float* __restrict__ W_in,
                const float* __restrict__ b_in, const float* __restrict__ b_rec,
                float* __restrict__ inp)
{
    __shared__ float smem[64 * 130];
    const int t = threadIdx.x;
    const int l = t & 63, w = t >> 6;
    const int r0 = blockIdx.x * 64;

    float2* xs2 = (float2*)smem;                // [64][65] float2
    for (int idx = t; idx < 64 * 64; idx += 256) {
        int row = idx >> 6, c2 = idx & 63;
        xs2[row * 65 + c2] = ((const float2*)x)[(size_t)(r0 + row) * 64 + c2];
    }
    __syncthreads();
    float xr[128];
#pragma unroll
    for (int i = 0; i < 64; ++i) {
        float2 v = xs2[l * 65 + i];
        xr[2 * i] = v.x; xr[2 * i + 1] = v.y;
    }
    __syncthreads();

    for (int ph = 0; ph < 2; ++ph) {
        for (int i = 0; i < 32; ++i) {
            const int hh = __builtin_amdgcn_readfirstlane(128 * ph + 32 * w + i);
            const float4* wr = (const float4*)(W_in + (size_t)hh * II);
            float a0 = b_in[hh] + b_rec[hh], a1 = 0.f, a2 = 0.f, a3 = 0.f;
#pragma unroll
            for (int j = 0; j < 32; ++j) {
                float4 wv = wr[j];
                a0 = fmaf(wv.x, xr[4 * j + 0], a0);
                a1 = fmaf(wv.y, xr[4 * j + 1], a1);
                a2 = fmaf(wv.z, xr[4 * j + 2], a2);
                a3 = fmaf(wv.w, xr[4 * j + 3], a3);
            }
            smem[l * 128 + (((hh & 127) + l) & 127)] = a0 + a1 + a2 + a3;
        }
        __syncthreads();
        for (int k = 0; k < 32; ++k) {
            int idx = k * 256 + t;
            int row = idx >> 7, c = idx & 127;
            inp[(size_t)(r0 + row) * HH + 128 * ph + c] = smem[row * 128 + ((c + row) & 127)];
        }
        __syncthreads();
    }
}

// ---------------------------------------------------------------------------
// Kernel B: persistent recurrence, 4-waves-per-SIMD stall-hiding version.
// Round-8 established: packed-f16 MACs issue at ~4cy/wave (same MAC rate as
// f32 fma) -> issue floor is 1536 cy/SIMD/step regardless of instruction.
// r6's 2-wave wall = 2617 cy (busy 1843, stall 774). This kernel keeps r6's
// dot2/f32-acc math but runs 16 waves (4/SIMD) to hide the stall component.
//   - 1024 thr: thread t -> (r = t>>2, qt = t&3): row r x k-quarter
//     [qt*64, qt*64+64), 3 gates = 96 packed-weight dwords/thread.
//   - __launch_bounds__(1024, 4): exactly 128-VGPR budget (r5's failure was
//     the compiler choosing 64 VGPR for a phantom 2-blocks/CU target and
//     pushing ~70 dwords to AGPR).
//   - hT: 2 x 512B, uint4-XOR swizzle (r4-proven): logical uint4 u = qt*8+c
//     stored at qt*8+(c^qt). Read iteration c: 4 distinct disjoint bank-quads
//     (16-lane broadcast each). Write: ds_write_b16 per row-owner (qt==0),
//     2 half-writes/dword = 2-way = free.
//   - reduce: __shfl_xor 1,2 (quad DPP); pointwise redundant on quad lanes.
//   - ONE lgkm-only barrier per step; inp prefetched 1 step ahead.
// ---------------------------------------------------------------------------
__global__ __launch_bounds__(1024, 4)
void ltc_recurrent(const float* __restrict__ W_rec,
                   const float* __restrict__ W_cg,  const float* __restrict__ b_cg,
                   const float* __restrict__ W_eg,  const float* __restrict__ b_eg,
                   const float* __restrict__ tau,
                   float* __restrict__ st)          // [B,S,H]: inp staged in, states out
{
    const int b = blockIdx.x, t = threadIdx.x;
    const int r = t >> 2, qt = t & 3;               // row 0..255, k-quarter 0..3

    __shared__ __align__(16) uint4 hT[2][32];       // 2 x 512B packed-f16 h, swizzled

    unsigned wR[32], wC[32], wE[32];
#define LOADW(dst, base) { const float4* p4_ = (const float4*)(base); \
    _Pragma("unroll") for (int j = 0; j < 16; ++j) { float4 v_ = p4_[j]; \
        dst[2 * j] = packh(v_.x, v_.y); dst[2 * j + 1] = packh(v_.z, v_.w); } }
    LOADW(wR, W_rec + (size_t)r * HH + qt * 64)
    LOADW(wC, W_cg  + (size_t)r * HH + qt * 64)
    LOADW(wE, W_eg  + (size_t)r * HH + qt * 64)
#undef LOADW

    const float ti = 1.0f / tau[r];
    const float bC = b_cg[r], bE = b_eg[r];

    // swizzled write byte-offset for this row's f16 slot (logical dword r>>1):
    //   logical uint4 u = r>>3; storage = (u&~7) | ((u&7) ^ (u>>3))
    const int u_log = r >> 3;
    const int u_st  = (u_log & ~7) | ((u_log & 7) ^ (u_log >> 3));
    const int hoff  = u_st * 16 + ((r >> 1) & 3) * 4 + (r & 1) * 2;

    float* stb = st + (size_t)b * SS * HH;
    float h = 0.f;                                   // state for row r
    float inpC = stb[r];                             // inp(0, r); b_in+b_rec folded

    if (t < 32) hT[0][t] = make_uint4(0u, 0u, 0u, 0u);
    __syncthreads();

    for (int s = 0; s < SS; ++s) {
        const int cur = s & 1, nxt = cur ^ 1;

        float pf = 0.f;
        const bool dopf = (s + 1 < SS);
        if (dopf) pf = stb[(size_t)(s + 1) * HH + r];

        const uint4* hb = hT[cur];
        float aR0 = 0.f, aR1 = 0.f, aC0 = 0.f, aC1 = 0.f, aE0 = 0.f, aE1 = 0.f;
#pragma unroll
        for (int c = 0; c < 8; ++c) {
            uint4 q = hb[qt * 8 + (c ^ qt)];
            aR0 = dot2acc(wR[4 * c + 0], q.x, aR0);
            aC0 = dot2acc(wC[4 * c + 0], q.x, aC0);
            aE0 = dot2acc(wE[4 * c + 0], q.x, aE0);
            aR1 = dot2acc(wR[4 * c + 1], q.y, aR1);
            aC1 = dot2acc(wC[4 * c + 1], q.y, aC1);
            aE1 = dot2acc(wE[4 * c + 1], q.y, aE1);
            aR0 = dot2acc(wR[4 * c + 2], q.z, aR0);
            aC0 = dot2acc(wC[4 * c + 2], q.z, aC0);
            aE0 = dot2acc(wE[4 * c + 2], q.z, aE0);
            aR1 = dot2acc(wR[4 * c + 3], q.w, aR1);
            aC1 = dot2acc(wC[4 * c + 3], q.w, aC1);
            aE1 = dot2acc(wE[4 * c + 3], q.w, aE1);
        }
        float aR = aR0 + aR1, aC = aC0 + aC1, aE = aE0 + aE1;
        // reduce across the 4 k-quarters (quad DPP, VALU pipe)
        aR += __shfl_xor(aR, 1); aR += __shfl_xor(aR, 2);
        aC += __shfl_xor(aC, 1); aC += __shfl_xor(aC, 2);
        aE += __shfl_xor(aE, 1); aE += __shfl_xor(aE, 2);

        // pointwise for row r (all 4 quad lanes bitwise-identical)
        float cm = fsigmoid(aC + bC);
        float em = ftanh(aE + bE);
        float p  = inpC + aR;                        // rec bias folded into inp
        float rl = fmaxf(p, 0.f);
        float dh = (rl - h) * ti * cm + 0.1f * em;
        h = fmaf(0.1f, dh, h);

        if (qt == 0) {
            *(__fp16*)((char*)hT[nxt] + hoff) = (__fp16)h;   // ds_write_b16
            stb[(size_t)s * HH + r] = h;                     // states (f32)
        }
        inpC = pf;
        bar_lds();                                   // hT[nxt] visible next step
    }
}

// ---------------------------------------------------------------------------
// Kernel C: outputs[row,o] = b_out[o] + states[row,:] @ W_out[o,:]
// readfirstlane scalar-W trick (round-7 verified).
// ---------------------------------------------------------------------------
__global__ __launch_bounds__(256)
void ltc_out(const float* __restrict__ states, const float* __restrict__ W_out,
             const float* __restrict__ b_out, float* __restrict__ outputs)
{
    __shared__ float smem[64 * 130];
    const int t = threadIdx.x;
    const int l = t & 63, w = t >> 6;
    const int r0 = blockIdx.x * 64;

    float osacc[32];
#pragma unroll
    for (int i = 0; i < 32; ++i)
        osacc[i] = b_out[__builtin_amdgcn_readfirstlane(32 * w + i)];

    float2* xs2 = (float2*)smem;                // [64][65] float2
    for (int ph = 0; ph < 2; ++ph) {
        for (int idx = t; idx < 64 * 64; idx += 256) {
            int row = idx >> 6, c2 = idx & 63;
            xs2[row * 65 + c2] = ((const float2*)states)[(size_t)(r0 + row) * 128 + ph * 64 + c2];
        }
        __syncthreads();
        float xr[128];
#pragma unroll
        for (int i = 0; i < 64; ++i) {
            float2 v = xs2[l * 65 + i];
            xr[2 * i] = v.x; xr[2 * i + 1] = v.y;
        }
        __syncthreads();

        for (int i = 0; i < 32; ++i) {
            const int oo = __builtin_amdgcn_readfirstlane(32 * w + i);
            const float4* wr = (const float4*)(W_out + (size_t)oo * HH + ph * 128);
            float a0 = 0.f, a1 = 0.f, a2 = 0.f, a3 = 0.f;
#pragma unroll
            for (int j = 0; j < 32; ++j) {
                float4 wv = wr[j];
                a0 = fmaf(wv.x, xr[4 * j + 0], a0);
                a1 = fmaf(wv.y, xr[4 * j + 1], a1);
                a2 = fmaf(wv.z, xr[4 * j + 2], a2);
                a3 = fmaf(wv.w, xr[4 * j + 3], a3);
            }
            osacc[i] += (a0 + a1) + (a2 + a3);
        }
    }

    __syncthreads();
#pragma unroll
    for (int i = 0; i < 32; ++i)
        smem[l * 128 + ((32 * w + i + l) & 127)] = osacc[i];
    __syncthreads();
    for (int k = 0; k < 32; ++k) {
        int idx = k * 256 + t;
        int row = idx >> 7, c = idx & 127;
        outputs[(size_t)(r0 + row) * OO + c] = smem[row * 128 + ((c + row) & 127)];
    }
}

extern "C" void kernel_launch(void* const* d_in, const int* in_sizes, int n_in,
                              void* d_out, int out_size, void* d_ws, size_t ws_size,
                              hipStream_t stream) {
    const float* x      = (const float*)d_in[0];
    const float* W_in   = (const float*)d_in[1];
    const float* b_in   = (const float*)d_in[2];
    const float* W_rec  = (const float*)d_in[3];
    const float* b_rec  = (const float*)d_in[4];
    const float* W_out  = (const float*)d_in[5];
    const float* b_out  = (const float*)d_in[6];
    const float* W_cg   = (const float*)d_in[7];
    const float* b_cg   = (const float*)d_in[8];
    const float* W_eg   = (const float*)d_in[9];
    const float* b_eg   = (const float*)d_in[10];
    const float* tau    = (const float*)d_in[11];

    float* outputs = (float*)d_out;                       // [B,S,O]
    float* states  = outputs + (size_t)BB * SS * OO;      // [B,S,H] (inp staging -> states)

    hipLaunchKernelGGL(ltc_inproj, dim3(BB * SS / 64), dim3(256), 0, stream,
                       x, W_in, b_in, b_rec, states);
    hipLaunchKernelGGL(ltc_recurrent, dim3(BB), dim3(1024), 0, stream,
                       W_rec, W_cg, b_cg, W_eg, b_eg, tau, states);
    hipLaunchKernelGGL(ltc_out, dim3(BB * SS / 64), dim3(256), 0, stream,
                       states, W_out, b_out, outputs);
}

// Round 10
// 1305.075 us; speedup vs baseline: 1.6367x; 1.6367x over previous
//
#include <hip/hip_runtime.h>
#include <hip/hip_fp16.h>

#define BB 64
#define SS 1024
#define II 128
#define HH 256
#define OO 128

#if __has_builtin(__builtin_amdgcn_fdot2)
#define HAVE_DOT2 1
#endif

typedef __fp16 h2_t __attribute__((ext_vector_type(2)));
typedef _Float16 f16x8 __attribute__((ext_vector_type(8)));
typedef float f32x4 __attribute__((ext_vector_type(4)));

__device__ __forceinline__ unsigned packh(float a, float b) {
    union { h2_t h; unsigned u; } cv;
    cv.h = __builtin_amdgcn_cvt_pkrtz(a, b);   // v_cvt_pkrtz_f16_f32
    return cv.u;
}

__device__ __forceinline__ float dot2acc(unsigned w, unsigned h, float acc) {
#ifdef HAVE_DOT2
    union { unsigned u; h2_t h; } cw, ch;
    cw.u = w; ch.u = h;
    return __builtin_amdgcn_fdot2(cw.h, ch.h, acc, false);
#else
    union { unsigned u; __half2 h; } cw, ch;
    cw.u = w; ch.u = h;
    float2 a = __half22float2(cw.h), b = __half22float2(ch.h);
    return fmaf(a.x, b.x, fmaf(a.y, b.y, acc));
#endif
}

// fast transcendentals: error ~1e-6, below the f16-weight noise floor.
__device__ __forceinline__ float fsigmoid(float x) {
    float e = __builtin_amdgcn_exp2f(-1.4426950408889634f * x);
    return __builtin_amdgcn_rcpf(1.0f + e);
}
__device__ __forceinline__ float ftanh(float x) {
    float e = __builtin_amdgcn_exp2f(2.8853900817779268f * x);   // e^(2x)
    return 1.0f - 2.0f * __builtin_amdgcn_rcpf(1.0f + e);
}

// barrier without vmcnt drain: per-step global store / prefetch stay in flight.
__device__ __forceinline__ void bar_lds() {
    asm volatile("s_waitcnt lgkmcnt(0)\n\ts_barrier" ::: "memory");
}

// ---------------------------------------------------------------------------
// Kernel P: pack W_in [256][128] f32 and W_out [128][256] f32 -> f16 arrays
// in the workspace (each 32768 halves = 64KB). Lets the GEMM kernels load
// B-fragments as a single dwordx4.
// ---------------------------------------------------------------------------
__global__ __launch_bounds__(256)
void ltc_packw(const float* __restrict__ Win, const float* __restrict__ Wout,
               unsigned* __restrict__ WhI, unsigned* __restrict__ WhO)
{
    const int tid = blockIdx.x * 256 + threadIdx.x;       // 0..8191
    const float* src = (tid < 4096) ? Win : Wout;
    unsigned* dst    = (tid < 4096) ? WhI : WhO;
    const int k = tid & 4095;                             // 4096 thr x 8 floats
    const float4* s4 = (const float4*)(src + k * 8);
    float4 a = s4[0], b = s4[1];
    uint4 o;
    o.x = packh(a.x, a.y); o.y = packh(a.z, a.w);
    o.z = packh(b.x, b.y); o.w = packh(b.z, b.w);
    ((uint4*)dst)[k] = o;
}

// ---------------------------------------------------------------------------
// Kernel A (MFMA): inp[m, n] = x[m, :128] @ W_in[n, :128] + (b_in+b_rec)[n]
// m = flattened (b,t) 0..65535, n = h 0..255. 1024 blocks x 256 thr (4 waves).
// Wave wv owns rows m0..m0+15; loops all 16 n-tiles; K=128 -> 4 MFMA/tile.
// Fragment layout hardware-verified in round 3 (passed, absmax unchanged):
//   A-frag: row = l&15, k = ks*32 + (l>>4)*8 + j   (8 consecutive k)
//   B-frag: col = l&15, same k pattern  -> one dwordx4 from packed Wh row
//   D:      col = l&15, row = 4*(l>>4) + reg
// ---------------------------------------------------------------------------
__global__ __launch_bounds__(256)
void ltc_inproj_mfma(const float* __restrict__ x, const unsigned* __restrict__ Wh,
                     const float* __restrict__ b_in, const float* __restrict__ b_rec,
                     float* __restrict__ inp)
{
    const int t = threadIdx.x;
    const int wv = t >> 6, l = t & 63;
    const int l16 = l & 15, q = l >> 4;

    union F { unsigned u[4]; uint4 q4; f16x8 v; };

    const size_t marow = (size_t)blockIdx.x * 64 + wv * 16 + l16;  // A-frag row
    F xa[4];
#pragma unroll
    for (int ks = 0; ks < 4; ++ks) {
        const float4* px = (const float4*)(x + marow * II + ks * 32 + q * 8);
        float4 a = px[0], b = px[1];
        xa[ks].u[0] = packh(a.x, a.y); xa[ks].u[1] = packh(a.z, a.w);
        xa[ks].u[2] = packh(b.x, b.y); xa[ks].u[3] = packh(b.z, b.w);
    }

    const size_t drow = (size_t)blockIdx.x * 64 + wv * 16 + 4 * q;  // D row base
    for (int nt = 0; nt < 16; ++nt) {
        const int n = nt * 16 + l16;
        const float bb = b_in[n] + b_rec[n];
        f32x4 acc = {bb, bb, bb, bb};
#pragma unroll
        for (int ks = 0; ks < 4; ++ks) {
            F wb;
            wb.q4 = *(const uint4*)(Wh + ((size_t)n * II + ks * 32 + q * 8) / 2);
            acc = __builtin_amdgcn_mfma_f32_16x16x32_f16(xa[ks].v, wb.v, acc, 0, 0, 0);
        }
#pragma unroll
        for (int r = 0; r < 4; ++r)
            inp[(drow + r) * HH + n] = acc[r];
    }
}

// ---------------------------------------------------------------------------
// Kernel B: persistent recurrence — round-6 verified best (1117us, VGPR 128).
// 64 blocks x 512 thr; (r = t>>1, half = t&1); cross-half __shfl_xor(1);
// h_p double-buffered + pad; ONE lgkm-only barrier per step.
// Round 7-9 established: packed-f16 MACs issue ~4cy/wave -> issue floor
// 1536 cy/SIMD/step; 3- and 4-wave variants regress (barrier-synced LDS
// burst + register budget). This structure is the session's measured best.
// ---------------------------------------------------------------------------
__global__ __launch_bounds__(512, 1)
void ltc_recurrent(const float* __restrict__ W_rec,
                   const float* __restrict__ W_cg,  const float* __restrict__ b_cg,
                   const float* __restrict__ W_eg,  const float* __restrict__ b_eg,
                   const float* __restrict__ tau,
                   float* __restrict__ st)          // [B,S,H]: inp staged in, states out
{
    const int b = blockIdx.x, t = threadIdx.x;
    const int r = t >> 1, half = t & 1;

    // [buf][132]: dwords 0..63 = packed pairs 0..63, pad 64..67, 68..131 = pairs 64..127
    __shared__ __align__(16) unsigned h_p[2][132];

    unsigned wR[64], wC[64], wE[64];
    {
        const float4* R4 = (const float4*)(W_rec + (size_t)r * HH + half * 128);
        const float4* C4 = (const float4*)(W_cg  + (size_t)r * HH + half * 128);
        const float4* E4 = (const float4*)(W_eg  + (size_t)r * HH + half * 128);
#pragma unroll
        for (int j = 0; j < 32; ++j) {
            float4 v = R4[j]; wR[2 * j] = packh(v.x, v.y); wR[2 * j + 1] = packh(v.z, v.w);
        }
#pragma unroll
        for (int j = 0; j < 32; ++j) {
            float4 v = C4[j]; wC[2 * j] = packh(v.x, v.y); wC[2 * j + 1] = packh(v.z, v.w);
        }
#pragma unroll
        for (int j = 0; j < 32; ++j) {
            float4 v = E4[j]; wE[2 * j] = packh(v.x, v.y); wE[2 * j + 1] = packh(v.z, v.w);
        }
    }

    const float ti = 1.0f / tau[r];
    const float bC = b_cg[r], bE = b_eg[r];

    float* stb = st + (size_t)b * SS * HH;
    float hr = 0.f;                    // f32 state for row r
    float inpC = stb[r];               // inp(0, r) — b_in+b_rec already folded

    if (t < 132) h_p[0][t] = 0u;
    bar_lds();

    for (int s = 0; s < SS; ++s) {
        float inpN = 0.f;
        if (s + 1 < SS) inpN = stb[(size_t)(s + 1) * HH + r];

        const uint4* hp4 = (const uint4*)(h_p[s & 1]) + half * 17;  // 17 uint4 = 68 dwords
        float aR0 = 0.f, aR1 = 0.f, aC0 = 0.f, aC1 = 0.f, aE0 = 0.f, aE1 = 0.f;
#pragma unroll
        for (int c = 0; c < 4; ++c) {                   // 4 chunks x 16 packed dwords
            uint4 q0 = hp4[c * 4 + 0], q1 = hp4[c * 4 + 1];
            uint4 q2 = hp4[c * 4 + 2], q3 = hp4[c * 4 + 3];
#define DOTQ(Q, k0, k1, k2, k3) \
            aR0 = dot2acc(wR[c * 16 + k0], Q.x, aR0); \
            aC0 = dot2acc(wC[c * 16 + k0], Q.x, aC0); \
            aE0 = dot2acc(wE[c * 16 + k0], Q.x, aE0); \
            aR1 = dot2acc(wR[c * 16 + k1], Q.y, aR1); \
            aC1 = dot2acc(wC[c * 16 + k1], Q.y, aC1); \
            aE1 = dot2acc(wE[c * 16 + k1], Q.y, aE1); \
            aR0 = dot2acc(wR[c * 16 + k2], Q.z, aR0); \
            aC0 = dot2acc(wC[c * 16 + k2], Q.z, aC0); \
            aE0 = dot2acc(wE[c * 16 + k2], Q.z, aE0); \
            aR1 = dot2acc(wR[c * 16 + k3], Q.w, aR1); \
            aC1 = dot2acc(wC[c * 16 + k3], Q.w, aC1); \
            aE1 = dot2acc(wE[c * 16 + k3], Q.w, aE1);
            DOTQ(q0, 0, 1, 2, 3)
            DOTQ(q1, 4, 5, 6, 7)
            DOTQ(q2, 8, 9, 10, 11)
            DOTQ(q3, 12, 13, 14, 15)
#undef DOTQ
        }
        float aR = aR0 + aR1, aC = aC0 + aC1, aE = aE0 + aE1;
        aR += __shfl_xor(aR, 1);                         // cross-half reduce in-wave
        aC += __shfl_xor(aC, 1);
        aE += __shfl_xor(aE, 1);

        // pointwise for row r (both half-lanes compute identical values)
        float cm = fsigmoid(aC + bC);
        float em = ftanh(aE + bE);
        float p  = inpC + aR;
        float rl = fmaxf(p, 0.f);
        float dh = (rl - hr) * ti * cm + 0.1f * em;
        hr = fmaf(0.1f, dh, hr);

        // pack rows (r, r+1): t%4==0 threads (r even, half 0) grab neighbor h
        float hnb = __shfl_xor(hr, 2);
        if ((t & 3) == 0) {
            int wi = t >> 2;                             // pair index 0..127
            int wo = wi + ((wi >> 6) << 2);              // +4 pad for pairs >= 64
            h_p[(s + 1) & 1][wo] = packh(hr, hnb);
            float2 hv; hv.x = hr; hv.y = hnb;
            ((float2*)(stb + (size_t)s * HH))[wi] = hv;
        }
        inpC = inpN;
        bar_lds();                                       // h_p[(s+1)&1] visible
    }
}

// ---------------------------------------------------------------------------
// Kernel C (MFMA): outputs[m, n] = states[m, :256] @ W_out[n, :256] + b_out[n]
// Same fragment mapping as kernel A; K=256 (8 k-steps), N=128 (8 n-tiles).
// ---------------------------------------------------------------------------
__global__ __launch_bounds__(256)
void ltc_out_mfma(const float* __restrict__ states, const unsigned* __restrict__ Wh,
                  const float* __restrict__ b_out, float* __restrict__ outputs)
{
    const int t = threadIdx.x;
    const int wv = t >> 6, l = t & 63;
    const int l16 = l & 15, q = l >> 4;

    union F { unsigned u[4]; uint4 q4; f16x8 v; };

    const size_t marow = (size_t)blockIdx.x * 64 + wv * 16 + l16;  // A-frag row
    F sa[8];
#pragma unroll
    for (int ks = 0; ks < 8; ++ks) {
        const float4* ps = (const float4*)(states + marow * HH + ks * 32 + q * 8);
        float4 a = ps[0], b = ps[1];
        sa[ks].u[0] = packh(a.x, a.y); sa[ks].u[1] = packh(a.z, a.w);
        sa[ks].u[2] = packh(b.x, b.y); sa[ks].u[3] = packh(b.z, b.w);
    }

    const size_t drow = (size_t)blockIdx.x * 64 + wv * 16 + 4 * q;  // D row base
    for (int nt = 0; nt < 8; ++nt) {
        const int n = nt * 16 + l16;
        const float bb = b_out[n];
        f32x4 acc = {bb, bb, bb, bb};
#pragma unroll
        for (int ks = 0; ks < 8; ++ks) {
            F wb;
            wb.q4 = *(const uint4*)(Wh + ((size_t)n * HH + ks * 32 + q * 8) / 2);
            acc = __builtin_amdgcn_mfma_f32_16x16x32_f16(sa[ks].v, wb.v, acc, 0, 0, 0);
        }
#pragma unroll
        for (int r = 0; r < 4; ++r)
            outputs[(drow + r) * OO + n] = acc[r];
    }
}

extern "C" void kernel_launch(void* const* d_in, const int* in_sizes, int n_in,
                              void* d_out, int out_size, void* d_ws, size_t ws_size,
                              hipStream_t stream) {
    const float* x      = (const float*)d_in[0];
    const float* W_in   = (const float*)d_in[1];
    const float* b_in   = (const float*)d_in[2];
    const float* W_rec  = (const float*)d_in[3];
    const float* b_rec  = (const float*)d_in[4];
    const float* W_out  = (const float*)d_in[5];
    const float* b_out  = (const float*)d_in[6];
    const float* W_cg   = (const float*)d_in[7];
    const float* b_cg   = (const float*)d_in[8];
    const float* W_eg   = (const float*)d_in[9];
    const float* b_eg   = (const float*)d_in[10];
    const float* tau    = (const float*)d_in[11];

    float* outputs = (float*)d_out;                       // [B,S,O]
    float* states  = outputs + (size_t)BB * SS * OO;      // [B,S,H] (inp staging -> states)

    unsigned* WhI = (unsigned*)d_ws;                      // 16384 dwords = 64KB
    unsigned* WhO = WhI + 16384;                          // 16384 dwords = 64KB

    hipLaunchKernelGGL(ltc_packw, dim3(32), dim3(256), 0, stream,
                       W_in, W_out, WhI, WhO);
    hipLaunchKernelGGL(ltc_inproj_mfma, dim3(BB * SS / 64), dim3(256), 0, stream,
                       x, WhI, b_in, b_rec, states);
    hipLaunchKernelGGL(ltc_recurrent, dim3(BB), dim3(512), 0, stream,
                       W_rec, W_cg, b_cg, W_eg, b_eg, tau, states);
    hipLaunchKernelGGL(ltc_out_mfma, dim3(BB * SS / 64), dim3(256), 0, stream,
                       states, WhO, b_out, outputs);
}

// Round 11
// 1270.772 us; speedup vs baseline: 1.6809x; 1.0270x over previous
//
#include <hip/hip_runtime.h>
#include <hip/hip_fp16.h>

#define BB 64
#define SS 1024
#define II 128
#define HH 256
#define OO 128

#if __has_builtin(__builtin_amdgcn_fdot2)
#define HAVE_DOT2 1
#endif

typedef __fp16 h2_t __attribute__((ext_vector_type(2)));
typedef _Float16 f16x8 __attribute__((ext_vector_type(8)));
typedef float f32x4 __attribute__((ext_vector_type(4)));

__device__ __forceinline__ unsigned packh(float a, float b) {
    union { h2_t h; unsigned u; } cv;
    cv.h = __builtin_amdgcn_cvt_pkrtz(a, b);   // v_cvt_pkrtz_f16_f32
    return cv.u;
}

__device__ __forceinline__ float dot2acc(unsigned w, unsigned h, float acc) {
#ifdef HAVE_DOT2
    union { unsigned u; h2_t h; } cw, ch;
    cw.u = w; ch.u = h;
    return __builtin_amdgcn_fdot2(cw.h, ch.h, acc, false);
#else
    union { unsigned u; __half2 h; } cw, ch;
    cw.u = w; ch.u = h;
    float2 a = __half22float2(cw.h), b = __half22float2(ch.h);
    return fmaf(a.x, b.x, fmaf(a.y, b.y, acc));
#endif
}

// fast transcendentals: error ~1e-6, below the f16-weight noise floor.
__device__ __forceinline__ float fsigmoid(float x) {
    float e = __builtin_amdgcn_exp2f(-1.4426950408889634f * x);
    return __builtin_amdgcn_rcpf(1.0f + e);
}
__device__ __forceinline__ float ftanh(float x) {
    float e = __builtin_amdgcn_exp2f(2.8853900817779268f * x);   // e^(2x)
    return 1.0f - 2.0f * __builtin_amdgcn_rcpf(1.0f + e);
}

// barrier without vmcnt drain: per-step global store / prefetch stay in flight.
__device__ __forceinline__ void bar_lds() {
    asm volatile("s_waitcnt lgkmcnt(0)\n\ts_barrier" ::: "memory");
}

// ---------------------------------------------------------------------------
// Kernel P: pack W_in / W_out to f16 in FRAGMENT ORDER so the GEMM kernels'
// B-fragment loads are fully coalesced (wave reads 1KB contiguous):
//   WhI uint4 idx = ((nt*4+ks)*4+q)*16 + l16  <- W_in [nt*16+l16][ks*32+q*8 ..+8]
//   WhO uint4 idx = ((nt*8+ks)*4+q)*16 + l16  <- W_out[nt*16+l16][ks*32+q*8 ..+8]
// ---------------------------------------------------------------------------
__global__ __launch_bounds__(256)
void ltc_packw(const float* __restrict__ Win, const float* __restrict__ Wout,
               uint4* __restrict__ WhI, uint4* __restrict__ WhO)
{
    const int tid = blockIdx.x * 256 + threadIdx.x;       // 0..12287
    const float* src;
    uint4* dst;
    if (tid < 4096) {                                     // W_in: 16nt x 4ks x 4q x 16l
        int l16 = tid & 15, q = (tid >> 4) & 3, ks = (tid >> 6) & 3, nt = tid >> 8;
        src = Win + (size_t)(nt * 16 + l16) * II + ks * 32 + q * 8;
        dst = WhI + tid;
    } else {                                              // W_out: 8nt x 8ks x 4q x 16l
        int t2 = tid - 4096;
        int l16 = t2 & 15, q = (t2 >> 4) & 3, ks = (t2 >> 6) & 7, nt = t2 >> 9;
        src = Wout + (size_t)(nt * 16 + l16) * HH + ks * 32 + q * 8;
        dst = WhO + t2;
    }
    float4 a = ((const float4*)src)[0], b = ((const float4*)src)[1];
    uint4 o;
    o.x = packh(a.x, a.y); o.y = packh(a.z, a.w);
    o.z = packh(b.x, b.y); o.w = packh(b.z, b.w);
    *dst = o;
}

// ---------------------------------------------------------------------------
// Kernel A (MFMA): inp[m,n] = x[m,:128] @ W_in[n,:128] + (b_in+b_rec)[n]
// Round-10 fix: fragment loads were 16B-per-lane scattered across rows
// (stride 512B) -> ~4x HBM read amplification. Now: x tile [64][128] staged
// in LDS via coalesced float4 loads (row pad 132 dwords: 16B-aligned, 2-way
// bank alias = free), fragments read from LDS; Wh read in fragment order
// (1KB contiguous per wave, L2-resident). MFMA mapping unchanged (r3/r10
// verified): A row=l&15, k=ks*32+(l>>4)*8+j; B col=l&15; D col=l&15,
// row=4*(l>>4)+reg.
// ---------------------------------------------------------------------------
__global__ __launch_bounds__(256)
void ltc_inproj_mfma(const float* __restrict__ x, const uint4* __restrict__ Wh,
                     const float* __restrict__ b_in, const float* __restrict__ b_rec,
                     float* __restrict__ inp)
{
    __shared__ float xs[64 * 132];                        // 33.8KB
    const int t = threadIdx.x;
    const int wv = t >> 6, l = t & 63;
    const int l16 = l & 15, q = l >> 4;
    const size_t m0 = (size_t)blockIdx.x * 64;

    const float4* xg = (const float4*)(x + m0 * II);      // 2048 float4s
#pragma unroll
    for (int i = 0; i < 8; ++i) {
        int f = i * 256 + t;
        int row = f >> 5, c4 = f & 31;
        *(float4*)&xs[row * 132 + c4 * 4] = xg[f];
    }
    __syncthreads();

    union F { unsigned u[4]; uint4 q4; f16x8 v; };
    F xa[4];
    const int arow = wv * 16 + l16;
#pragma unroll
    for (int ks = 0; ks < 4; ++ks) {
        const float* p = &xs[arow * 132 + ks * 32 + q * 8];
        float4 a = *(const float4*)p, b = *(const float4*)(p + 4);
        xa[ks].u[0] = packh(a.x, a.y); xa[ks].u[1] = packh(a.z, a.w);
        xa[ks].u[2] = packh(b.x, b.y); xa[ks].u[3] = packh(b.z, b.w);
    }

    const size_t drow = m0 + wv * 16 + 4 * q;             // D row base
    for (int nt = 0; nt < 16; ++nt) {
        const int n = nt * 16 + l16;
        const float bb = b_in[n] + b_rec[n];
        f32x4 acc = {bb, bb, bb, bb};
#pragma unroll
        for (int ks = 0; ks < 4; ++ks) {
            F wb;
            wb.q4 = Wh[((nt * 4 + ks) * 4 + q) * 16 + l16];   // coalesced 1KB/wave
            acc = __builtin_amdgcn_mfma_f32_16x16x32_f16(xa[ks].v, wb.v, acc, 0, 0, 0);
        }
#pragma unroll
        for (int r = 0; r < 4; ++r)
            inp[(drow + r) * HH + n] = acc[r];            // aligned 64B segments
    }
}

// ---------------------------------------------------------------------------
// Kernel B: persistent recurrence — round-6 verified best (1117-1127us).
// Session-established facts: VALU MAC rate is the invariant (dot2 / pk_fma /
// 2x fma_f32 all ~4cy per 2 MACs per wave) -> issue floor 1536 cy/SIMD/step;
// occupancy variants {2w/192d, 3w/128d, 4w/96d} measured {2617, 2900, 4080}
// cy/step -> this 2-wave structure is the optimum. Unchanged.
// ---------------------------------------------------------------------------
__global__ __launch_bounds__(512, 1)
void ltc_recurrent(const float* __restrict__ W_rec,
                   const float* __restrict__ W_cg,  const float* __restrict__ b_cg,
                   const float* __restrict__ W_eg,  const float* __restrict__ b_eg,
                   const float* __restrict__ tau,
                   float* __restrict__ st)          // [B,S,H]: inp staged in, states out
{
    const int b = blockIdx.x, t = threadIdx.x;
    const int r = t >> 1, half = t & 1;

    // [buf][132]: dwords 0..63 = packed pairs 0..63, pad 64..67, 68..131 = pairs 64..127
    __shared__ __align__(16) unsigned h_p[2][132];

    unsigned wR[64], wC[64], wE[64];
    {
        const float4* R4 = (const float4*)(W_rec + (size_t)r * HH + half * 128);
        const float4* C4 = (const float4*)(W_cg  + (size_t)r * HH + half * 128);
        const float4* E4 = (const float4*)(W_eg  + (size_t)r * HH + half * 128);
#pragma unroll
        for (int j = 0; j < 32; ++j) {
            float4 v = R4[j]; wR[2 * j] = packh(v.x, v.y); wR[2 * j + 1] = packh(v.z, v.w);
        }
#pragma unroll
        for (int j = 0; j < 32; ++j) {
            float4 v = C4[j]; wC[2 * j] = packh(v.x, v.y); wC[2 * j + 1] = packh(v.z, v.w);
        }
#pragma unroll
        for (int j = 0; j < 32; ++j) {
            float4 v = E4[j]; wE[2 * j] = packh(v.x, v.y); wE[2 * j + 1] = packh(v.z, v.w);
        }
    }

    const float ti = 1.0f / tau[r];
    const float bC = b_cg[r], bE = b_eg[r];

    float* stb = st + (size_t)b * SS * HH;
    float hr = 0.f;                    // f32 state for row r
    float inpC = stb[r];               // inp(0, r) — b_in+b_rec already folded

    if (t < 132) h_p[0][t] = 0u;
    bar_lds();

    for (int s = 0; s < SS; ++s) {
        float inpN = 0.f;
        if (s + 1 < SS) inpN = stb[(size_t)(s + 1) * HH + r];

        const uint4* hp4 = (const uint4*)(h_p[s & 1]) + half * 17;  // 17 uint4 = 68 dwords
        float aR0 = 0.f, aR1 = 0.f, aC0 = 0.f, aC1 = 0.f, aE0 = 0.f, aE1 = 0.f;
#pragma unroll
        for (int c = 0; c < 4; ++c) {                   // 4 chunks x 16 packed dwords
            uint4 q0 = hp4[c * 4 + 0], q1 = hp4[c * 4 + 1];
            uint4 q2 = hp4[c * 4 + 2], q3 = hp4[c * 4 + 3];
#define DOTQ(Q, k0, k1, k2, k3) \
            aR0 = dot2acc(wR[c * 16 + k0], Q.x, aR0); \
            aC0 = dot2acc(wC[c * 16 + k0], Q.x, aC0); \
            aE0 = dot2acc(wE[c * 16 + k0], Q.x, aE0); \
            aR1 = dot2acc(wR[c * 16 + k1], Q.y, aR1); \
            aC1 = dot2acc(wC[c * 16 + k1], Q.y, aC1); \
            aE1 = dot2acc(wE[c * 16 + k1], Q.y, aE1); \
            aR0 = dot2acc(wR[c * 16 + k2], Q.z, aR0); \
            aC0 = dot2acc(wC[c * 16 + k2], Q.z, aC0); \
            aE0 = dot2acc(wE[c * 16 + k2], Q.z, aE0); \
            aR1 = dot2acc(wR[c * 16 + k3], Q.w, aR1); \
            aC1 = dot2acc(wC[c * 16 + k3], Q.w, aC1); \
            aE1 = dot2acc(wE[c * 16 + k3], Q.w, aE1);
            DOTQ(q0, 0, 1, 2, 3)
            DOTQ(q1, 4, 5, 6, 7)
            DOTQ(q2, 8, 9, 10, 11)
            DOTQ(q3, 12, 13, 14, 15)
#undef DOTQ
        }
        float aR = aR0 + aR1, aC = aC0 + aC1, aE = aE0 + aE1;
        aR += __shfl_xor(aR, 1);                         // cross-half reduce in-wave
        aC += __shfl_xor(aC, 1);
        aE += __shfl_xor(aE, 1);

        // pointwise for row r (both half-lanes compute identical values)
        float cm = fsigmoid(aC + bC);
        float em = ftanh(aE + bE);
        float p  = inpC + aR;
        float rl = fmaxf(p, 0.f);
        float dh = (rl - hr) * ti * cm + 0.1f * em;
        hr = fmaf(0.1f, dh, hr);

        // pack rows (r, r+1): t%4==0 threads (r even, half 0) grab neighbor h
        float hnb = __shfl_xor(hr, 2);
        if ((t & 3) == 0) {
            int wi = t >> 2;                             // pair index 0..127
            int wo = wi + ((wi >> 6) << 2);              // +4 pad for pairs >= 64
            h_p[(s + 1) & 1][wo] = packh(hr, hnb);
            float2 hv; hv.x = hr; hv.y = hnb;
            ((float2*)(stb + (size_t)s * HH))[wi] = hv;
        }
        inpC = inpN;
        bar_lds();                                       // h_p[(s+1)&1] visible
    }
}

// ---------------------------------------------------------------------------
// Kernel C (MFMA): outputs[m,n] = states[m,:256] @ W_out[n,:256] + b_out[n]
// Same coalescing fix as kernel A: states tile [64][256] staged in LDS
// (row pad 260 dwords: 16B-aligned, 2-way bank alias = free); Wh_out read
// in fragment order.
// ---------------------------------------------------------------------------
__global__ __launch_bounds__(256)
void ltc_out_mfma(const float* __restrict__ states, const uint4* __restrict__ Wh,
                  const float* __restrict__ b_out, float* __restrict__ outputs)
{
    __shared__ float xs[64 * 260];                        // 65KB
    const int t = threadIdx.x;
    const int wv = t >> 6, l = t & 63;
    const int l16 = l & 15, q = l >> 4;
    const size_t m0 = (size_t)blockIdx.x * 64;

    const float4* sg = (const float4*)(states + m0 * HH); // 4096 float4s
#pragma unroll
    for (int i = 0; i < 16; ++i) {
        int f = i * 256 + t;
        int row = f >> 6, c4 = f & 63;
        *(float4*)&xs[row * 260 + c4 * 4] = sg[f];
    }
    __syncthreads();

    union F { unsigned u[4]; uint4 q4; f16x8 v; };
    F sa[8];
    const int arow = wv * 16 + l16;
#pragma unroll
    for (int ks = 0; ks < 8; ++ks) {
        const float* p = &xs[arow * 260 + ks * 32 + q * 8];
        float4 a = *(const float4*)p, b = *(const float4*)(p + 4);
        sa[ks].u[0] = packh(a.x, a.y); sa[ks].u[1] = packh(a.z, a.w);
        sa[ks].u[2] = packh(b.x, b.y); sa[ks].u[3] = packh(b.z, b.w);
    }

    const size_t drow = m0 + wv * 16 + 4 * q;             // D row base
    for (int nt = 0; nt < 8; ++nt) {
        const int n = nt * 16 + l16;
        const float bb = b_out[n];
        f32x4 acc = {bb, bb, bb, bb};
#pragma unroll
        for (int ks = 0; ks < 8; ++ks) {
            F wb;
            wb.q4 = Wh[((nt * 8 + ks) * 4 + q) * 16 + l16];   // coalesced 1KB/wave
            acc = __builtin_amdgcn_mfma_f32_16x16x32_f16(sa[ks].v, wb.v, acc, 0, 0, 0);
        }
#pragma unroll
        for (int r = 0; r < 4; ++r)
            outputs[(drow + r) * OO + n] = acc[r];        // aligned 64B segments
    }
}

extern "C" void kernel_launch(void* const* d_in, const int* in_sizes, int n_in,
                              void* d_out, int out_size, void* d_ws, size_t ws_size,
                              hipStream_t stream) {
    const float* x      = (const float*)d_in[0];
    const float* W_in   = (const float*)d_in[1];
    const float* b_in   = (const float*)d_in[2];
    const float* W_rec  = (const float*)d_in[3];
    const float* b_rec  = (const float*)d_in[4];
    const float* W_out  = (const float*)d_in[5];
    const float* b_out  = (const float*)d_in[6];
    const float* W_cg   = (const float*)d_in[7];
    const float* b_cg   = (const float*)d_in[8];
    const float* W_eg   = (const float*)d_in[9];
    const float* b_eg   = (const float*)d_in[10];
    const float* tau    = (const float*)d_in[11];

    float* outputs = (float*)d_out;                       // [B,S,O]
    float* states  = outputs + (size_t)BB * SS * OO;      // [B,S,H] (inp staging -> states)

    uint4* WhI = (uint4*)d_ws;                            // 4096 uint4 = 64KB
    uint4* WhO = WhI + 4096;                              // 8192 uint4 = 128KB

    hipLaunchKernelGGL(ltc_packw, dim3(48), dim3(256), 0, stream,
                       W_in, W_out, WhI, WhO);
    hipLaunchKernelGGL(ltc_inproj_mfma, dim3(BB * SS / 64), dim3(256), 0, stream,
                       x, WhI, b_in, b_rec, states);
    hipLaunchKernelGGL(ltc_recurrent, dim3(BB), dim3(512), 0, stream,
                       W_rec, W_cg, b_cg, W_eg, b_eg, tau, states);
    hipLaunchKernelGGL(ltc_out_mfma, dim3(BB * SS / 64), dim3(256), 0, stream,
                       states, WhO, b_out, outputs);
}

// Round 12
// 1266.054 us; speedup vs baseline: 1.6872x; 1.0037x over previous
//
#include <hip/hip_runtime.h>
#include <hip/hip_fp16.h>

#define BB 64
#define SS 1024
#define II 128
#define HH 256
#define OO 128

#if __has_builtin(__builtin_amdgcn_fdot2)
#define HAVE_DOT2 1
#endif

typedef __fp16 h2_t __attribute__((ext_vector_type(2)));
typedef _Float16 f16x8 __attribute__((ext_vector_type(8)));
typedef float f32x4 __attribute__((ext_vector_type(4)));

__device__ __forceinline__ unsigned packh(float a, float b) {
    union { h2_t h; unsigned u; } cv;
    cv.h = __builtin_amdgcn_cvt_pkrtz(a, b);   // v_cvt_pkrtz_f16_f32
    return cv.u;
}

__device__ __forceinline__ float dot2acc(unsigned w, unsigned h, float acc) {
#ifdef HAVE_DOT2
    union { unsigned u; h2_t h; } cw, ch;
    cw.u = w; ch.u = h;
    return __builtin_amdgcn_fdot2(cw.h, ch.h, acc, false);
#else
    union { unsigned u; __half2 h; } cw, ch;
    cw.u = w; ch.u = h;
    float2 a = __half22float2(cw.h), b = __half22float2(ch.h);
    return fmaf(a.x, b.x, fmaf(a.y, b.y, acc));
#endif
}

// fast transcendentals: error ~1e-6, below the f16-weight noise floor.
__device__ __forceinline__ float fsigmoid(float x) {
    float e = __builtin_amdgcn_exp2f(-1.4426950408889634f * x);
    return __builtin_amdgcn_rcpf(1.0f + e);
}
__device__ __forceinline__ float ftanh(float x) {
    float e = __builtin_amdgcn_exp2f(2.8853900817779268f * x);   // e^(2x)
    return 1.0f - 2.0f * __builtin_amdgcn_rcpf(1.0f + e);
}

// barrier without vmcnt drain: per-step global store / prefetch stay in flight.
__device__ __forceinline__ void bar_lds() {
    asm volatile("s_waitcnt lgkmcnt(0)\n\ts_barrier" ::: "memory");
}

// ---------------------------------------------------------------------------
// Kernel P: pack W_in / W_out to f16 in FRAGMENT ORDER so the GEMM kernels'
// B-fragment loads are fully coalesced (wave reads 1KB contiguous).
// ---------------------------------------------------------------------------
__global__ __launch_bounds__(256)
void ltc_packw(const float* __restrict__ Win, const float* __restrict__ Wout,
               uint4* __restrict__ WhI, uint4* __restrict__ WhO)
{
    const int tid = blockIdx.x * 256 + threadIdx.x;       // 0..12287
    const float* src;
    uint4* dst;
    if (tid < 4096) {                                     // W_in: 16nt x 4ks x 4q x 16l
        int l16 = tid & 15, q = (tid >> 4) & 3, ks = (tid >> 6) & 3, nt = tid >> 8;
        src = Win + (size_t)(nt * 16 + l16) * II + ks * 32 + q * 8;
        dst = WhI + tid;
    } else {                                              // W_out: 8nt x 8ks x 4q x 16l
        int t2 = tid - 4096;
        int l16 = t2 & 15, q = (t2 >> 4) & 3, ks = (t2 >> 6) & 7, nt = t2 >> 9;
        src = Wout + (size_t)(nt * 16 + l16) * HH + ks * 32 + q * 8;
        dst = WhO + t2;
    }
    float4 a = ((const float4*)src)[0], b = ((const float4*)src)[1];
    uint4 o;
    o.x = packh(a.x, a.y); o.y = packh(a.z, a.w);
    o.z = packh(b.x, b.y); o.w = packh(b.z, b.w);
    *dst = o;
}

// ---------------------------------------------------------------------------
// Kernel A (MFMA): inp[m,n] = x[m,:128] @ W_in[n,:128] + (b_in+b_rec)[n]
// Round-12: stage the x tile as PACKED F16 (identical packh math, done during
// staging) -> LDS 33.8KB -> 17.4KB; occupancy wave-slot-bound (~8 blocks/CU).
// Fragment = direct uint4 from LDS. MFMA mapping unchanged (r3/r10 verified).
// ---------------------------------------------------------------------------
__global__ __launch_bounds__(256)
void ltc_inproj_mfma(const float* __restrict__ x, const uint4* __restrict__ Wh,
                     const float* __restrict__ b_in, const float* __restrict__ b_rec,
                     float* __restrict__ inp)
{
    __shared__ unsigned xs[64 * 68];                      // 17.4KB packed f16
    const int t = threadIdx.x;
    const int wv = t >> 6, l = t & 63;
    const int l16 = l & 15, q = l >> 4;
    const size_t m0 = (size_t)blockIdx.x * 64;

    const float4* xg = (const float4*)(x + m0 * II);      // 2048 float4
#pragma unroll
    for (int i = 0; i < 8; ++i) {
        int f = i * 256 + t;                              // float4 id 0..2047
        float4 a = xg[f];
        int row = f >> 5, c4 = f & 31;                    // 32 float4 per row
        *(uint2*)&xs[row * 68 + c4 * 2] =
            make_uint2(packh(a.x, a.y), packh(a.z, a.w));
    }
    __syncthreads();

    union F { unsigned u[4]; uint4 q4; f16x8 v; };
    F xa[4];
    const int arow = wv * 16 + l16;
#pragma unroll
    for (int ks = 0; ks < 4; ++ks)
        xa[ks].q4 = *(const uint4*)&xs[arow * 68 + ks * 16 + q * 4];

    const size_t drow = m0 + wv * 16 + 4 * q;             // D row base
    for (int nt = 0; nt < 16; ++nt) {
        const int n = nt * 16 + l16;
        const float bb = b_in[n] + b_rec[n];
        f32x4 acc = {bb, bb, bb, bb};
#pragma unroll
        for (int ks = 0; ks < 4; ++ks) {
            F wb;
            wb.q4 = Wh[((nt * 4 + ks) * 4 + q) * 16 + l16];   // coalesced 1KB/wave
            acc = __builtin_amdgcn_mfma_f32_16x16x32_f16(xa[ks].v, wb.v, acc, 0, 0, 0);
        }
#pragma unroll
        for (int r = 0; r < 4; ++r)
            inp[(drow + r) * HH + n] = acc[r];            // aligned 64B segments
    }
}

// ---------------------------------------------------------------------------
// Kernel B: persistent recurrence — round-6 verified best (1117-1127us).
// Session-established: VALU MAC issue floor 1536 cy/SIMD/step; wall 2600 cy
// invariant across 8 structural variants (occupancy 2/3/4 waves, MFMA, LDS
// layouts, barrier semantics); residual = head ds-latency + serial pointwise
// tail + barrier skew at 2 waves/SIMD. PINNED — byte-identical to r6/r11.
// ---------------------------------------------------------------------------
__global__ __launch_bounds__(512, 1)
void ltc_recurrent(const float* __restrict__ W_rec,
                   const float* __restrict__ W_cg,  const float* __restrict__ b_cg,
                   const float* __restrict__ W_eg,  const float* __restrict__ b_eg,
                   const float* __restrict__ tau,
                   float* __restrict__ st)          // [B,S,H]: inp staged in, states out
{
    const int b = blockIdx.x, t = threadIdx.x;
    const int r = t >> 1, half = t & 1;

    // [buf][132]: dwords 0..63 = packed pairs 0..63, pad 64..67, 68..131 = pairs 64..127
    __shared__ __align__(16) unsigned h_p[2][132];

    unsigned wR[64], wC[64], wE[64];
    {
        const float4* R4 = (const float4*)(W_rec + (size_t)r * HH + half * 128);
        const float4* C4 = (const float4*)(W_cg  + (size_t)r * HH + half * 128);
        const float4* E4 = (const float4*)(W_eg  + (size_t)r * HH + half * 128);
#pragma unroll
        for (int j = 0; j < 32; ++j) {
            float4 v = R4[j]; wR[2 * j] = packh(v.x, v.y); wR[2 * j + 1] = packh(v.z, v.w);
        }
#pragma unroll
        for (int j = 0; j < 32; ++j) {
            float4 v = C4[j]; wC[2 * j] = packh(v.x, v.y); wC[2 * j + 1] = packh(v.z, v.w);
        }
#pragma unroll
        for (int j = 0; j < 32; ++j) {
            float4 v = E4[j]; wE[2 * j] = packh(v.x, v.y); wE[2 * j + 1] = packh(v.z, v.w);
        }
    }

    const float ti = 1.0f / tau[r];
    const float bC = b_cg[r], bE = b_eg[r];

    float* stb = st + (size_t)b * SS * HH;
    float hr = 0.f;                    // f32 state for row r
    float inpC = stb[r];               // inp(0, r) — b_in+b_rec already folded

    if (t < 132) h_p[0][t] = 0u;
    bar_lds();

    for (int s = 0; s < SS; ++s) {
        float inpN = 0.f;
        if (s + 1 < SS) inpN = stb[(size_t)(s + 1) * HH + r];

        const uint4* hp4 = (const uint4*)(h_p[s & 1]) + half * 17;  // 17 uint4 = 68 dwords
        float aR0 = 0.f, aR1 = 0.f, aC0 = 0.f, aC1 = 0.f, aE0 = 0.f, aE1 = 0.f;
#pragma unroll
        for (int c = 0; c < 4; ++c) {                   // 4 chunks x 16 packed dwords
            uint4 q0 = hp4[c * 4 + 0], q1 = hp4[c * 4 + 1];
            uint4 q2 = hp4[c * 4 + 2], q3 = hp4[c * 4 + 3];
#define DOTQ(Q, k0, k1, k2, k3) \
            aR0 = dot2acc(wR[c * 16 + k0], Q.x, aR0); \
            aC0 = dot2acc(wC[c * 16 + k0], Q.x, aC0); \
            aE0 = dot2acc(wE[c * 16 + k0], Q.x, aE0); \
            aR1 = dot2acc(wR[c * 16 + k1], Q.y, aR1); \
            aC1 = dot2acc(wC[c * 16 + k1], Q.y, aC1); \
            aE1 = dot2acc(wE[c * 16 + k1], Q.y, aE1); \
            aR0 = dot2acc(wR[c * 16 + k2], Q.z, aR0); \
            aC0 = dot2acc(wC[c * 16 + k2], Q.z, aC0); \
            aE0 = dot2acc(wE[c * 16 + k2], Q.z, aE0); \
            aR1 = dot2acc(wR[c * 16 + k3], Q.w, aR1); \
            aC1 = dot2acc(wC[c * 16 + k3], Q.w, aC1); \
            aE1 = dot2acc(wE[c * 16 + k3], Q.w, aE1);
            DOTQ(q0, 0, 1, 2, 3)
            DOTQ(q1, 4, 5, 6, 7)
            DOTQ(q2, 8, 9, 10, 11)
            DOTQ(q3, 12, 13, 14, 15)
#undef DOTQ
        }
        float aR = aR0 + aR1, aC = aC0 + aC1, aE = aE0 + aE1;
        aR += __shfl_xor(aR, 1);                         // cross-half reduce in-wave
        aC += __shfl_xor(aC, 1);
        aE += __shfl_xor(aE, 1);

        // pointwise for row r (both half-lanes compute identical values)
        float cm = fsigmoid(aC + bC);
        float em = ftanh(aE + bE);
        float p  = inpC + aR;
        float rl = fmaxf(p, 0.f);
        float dh = (rl - hr) * ti * cm + 0.1f * em;
        hr = fmaf(0.1f, dh, hr);

        // pack rows (r, r+1): t%4==0 threads (r even, half 0) grab neighbor h
        float hnb = __shfl_xor(hr, 2);
        if ((t & 3) == 0) {
            int wi = t >> 2;                             // pair index 0..127
            int wo = wi + ((wi >> 6) << 2);              // +4 pad for pairs >= 64
            h_p[(s + 1) & 1][wo] = packh(hr, hnb);
            float2 hv; hv.x = hr; hv.y = hnb;
            ((float2*)(stb + (size_t)s * HH))[wi] = hv;
        }
        inpC = inpN;
        bar_lds();                                       // h_p[(s+1)&1] visible
    }
}

// ---------------------------------------------------------------------------
// Kernel C (MFMA): outputs[m,n] = states[m,:256] @ W_out[n,:256] + b_out[n]
// Round-12: states tile staged as PACKED F16 -> LDS 65KB -> 33.8KB ->
// occupancy 2 -> 4 blocks/CU (memory-latency-bound kernel; the lever).
// ---------------------------------------------------------------------------
__global__ __launch_bounds__(256)
void ltc_out_mfma(const float* __restrict__ states, const uint4* __restrict__ Wh,
                  const float* __restrict__ b_out, float* __restrict__ outputs)
{
    __shared__ unsigned xs[64 * 132];                     // 33.8KB packed f16
    const int t = threadIdx.x;
    const int wv = t >> 6, l = t & 63;
    const int l16 = l & 15, q = l >> 4;
    const size_t m0 = (size_t)blockIdx.x * 64;

    const float4* sg = (const float4*)(states + m0 * HH); // 4096 float4
#pragma unroll
    for (int i = 0; i < 16; ++i) {
        int f = i * 256 + t;                              // float4 id 0..4095
        float4 a = sg[f];
        int row = f >> 6, c4 = f & 63;                    // 64 float4 per row
        *(uint2*)&xs[row * 132 + c4 * 2] =
            make_uint2(packh(a.x, a.y), packh(a.z, a.w));
    }
    __syncthreads();

    union F { unsigned u[4]; uint4 q4; f16x8 v; };
    F sa[8];
    const int arow = wv * 16 + l16;
#pragma unroll
    for (int ks = 0; ks < 8; ++ks)
        sa[ks].q4 = *(const uint4*)&xs[arow * 132 + ks * 16 + q * 4];

    const size_t drow = m0 + wv * 16 + 4 * q;             // D row base
    for (int nt = 0; nt < 8; ++nt) {
        const int n = nt * 16 + l16;
        const float bb = b_out[n];
        f32x4 acc = {bb, bb, bb, bb};
#pragma unroll
        for (int ks = 0; ks < 8; ++ks) {
            F wb;
            wb.q4 = Wh[((nt * 8 + ks) * 4 + q) * 16 + l16];   // coalesced 1KB/wave
            acc = __builtin_amdgcn_mfma_f32_16x16x32_f16(sa[ks].v, wb.v, acc, 0, 0, 0);
        }
#pragma unroll
        for (int r = 0; r < 4; ++r)
            outputs[(drow + r) * OO + n] = acc[r];        // aligned 64B segments
    }
}

extern "C" void kernel_launch(void* const* d_in, const int* in_sizes, int n_in,
                              void* d_out, int out_size, void* d_ws, size_t ws_size,
                              hipStream_t stream) {
    const float* x      = (const float*)d_in[0];
    const float* W_in   = (const float*)d_in[1];
    const float* b_in   = (const float*)d_in[2];
    const float* W_rec  = (const float*)d_in[3];
    const float* b_rec  = (const float*)d_in[4];
    const float* W_out  = (const float*)d_in[5];
    const float* b_out  = (const float*)d_in[6];
    const float* W_cg   = (const float*)d_in[7];
    const float* b_cg   = (const float*)d_in[8];
    const float* W_eg   = (const float*)d_in[9];
    const float* b_eg   = (const float*)d_in[10];
    const float* tau    = (const float*)d_in[11];

    float* outputs = (float*)d_out;                       // [B,S,O]
    float* states  = outputs + (size_t)BB * SS * OO;      // [B,S,H] (inp staging -> states)

    uint4* WhI = (uint4*)d_ws;                            // 4096 uint4 = 64KB
    uint4* WhO = WhI + 4096;                              // 8192 uint4 = 128KB

    hipLaunchKernelGGL(ltc_packw, dim3(48), dim3(256), 0, stream,
                       W_in, W_out, WhI, WhO);
    hipLaunchKernelGGL(ltc_inproj_mfma, dim3(BB * SS / 64), dim3(256), 0, stream,
                       x, WhI, b_in, b_rec, states);
    hipLaunchKernelGGL(ltc_recurrent, dim3(BB), dim3(512), 0, stream,
                       W_rec, W_cg, b_cg, W_eg, b_eg, tau, states);
    hipLaunchKernelGGL(ltc_out_mfma, dim3(BB * SS / 64), dim3(256), 0, stream,
                       states, WhO, b_out, outputs);
}